// Round 23
// baseline (455.976 us; speedup 1.0000x reference)
//
#include <hip/hip_runtime.h>
#include <hip/hip_bf16.h>
#include <cstddef>

typedef short bf16x8 __attribute__((ext_vector_type(8)));
typedef float f32x4 __attribute__((ext_vector_type(4)));

__device__ __forceinline__ unsigned short f2bf(float x) {
  __hip_bfloat16 h = __float2bfloat16(x);
  unsigned short u; __builtin_memcpy(&u, &h, 2); return u;
}
__device__ __forceinline__ float bf2f(unsigned short u) {
  unsigned int v = ((unsigned int)u) << 16; float f; __builtin_memcpy(&f, &v, 4); return f;
}
__device__ __forceinline__ void gload16(const unsigned short* g, unsigned short* l) {
  __builtin_amdgcn_global_load_lds(
      (const __attribute__((address_space(1))) void*)g,
      (__attribute__((address_space(3))) void*)l, 16, 0, 0);
}
__device__ __forceinline__ void pipe_sync() {
  asm volatile("s_waitcnt vmcnt(0)" ::: "memory");
  __builtin_amdgcn_s_barrier();
  __builtin_amdgcn_sched_barrier(0);
}
__device__ __forceinline__ void bar_only() {
  asm volatile("" ::: "memory");
  __builtin_amdgcn_s_barrier();
  __builtin_amdgcn_sched_barrier(0);
}

// ---------------- all weights fp32 -> bf16 (contiguous dst) ----------------
__global__ __launch_bounds__(256) void cvt_all(
    const float* __restrict__ qkv_w, const float* __restrict__ out_w,
    const float* __restrict__ fc1_w, const float* __restrict__ fc2_w,
    const float* __restrict__ outp_w, unsigned short* __restrict__ dst)
{
  int i = blockIdx.x * 256 + threadIdx.x;
  if (i >= 1576960) return;
  const float* src; int off;
  if (i < 786432)       { src = qkv_w;  off = i; }
  else if (i < 1048576) { src = out_w;  off = i - 786432; }
  else if (i < 1310720) { src = fc1_w;  off = i - 1048576; }
  else if (i < 1572864) { src = fc2_w;  off = i - 1310720; }
  else                  { src = outp_w; off = i - 1572864; }
  float4 v = *(const float4*)(src + (size_t)off * 4);
  ushort4 o;
  o.x = f2bf(v.x); o.y = f2bf(v.y); o.z = f2bf(v.z); o.w = f2bf(v.w);
  *(ushort4*)(dst + (size_t)i * 4) = o;
}

// ---------------- conv1d (circular, k=3) + positional embedding -> bf16 ------
__global__ __launch_bounds__(256) void conv_pe_kernel(
    const float* __restrict__ x, const float* __restrict__ cw,
    const float* __restrict__ cb, unsigned short* __restrict__ outb)
{
  const int L = 2048, CIN = 32;
  int b  = blockIdx.x >> 8;
  int l0 = (blockIdx.x & 255) << 3;
  int t  = threadIdx.x;
  __shared__ float xs[10][32];
  for (int idx = t; idx < 320; idx += 256) {
    int rr = idx >> 5, ci = idx & 31;
    int gl = (l0 - 1 + rr + L) & (L - 1);
    xs[rr][ci] = x[((size_t)b * L + gl) * CIN + ci];
  }
  __syncthreads();
  int e0 = t << 1;
  float acc0[8], acc1[8];
  float bb0 = cb[e0], bb1 = cb[e0 + 1];
#pragma unroll
  for (int li = 0; li < 8; li++) { acc0[li] = bb0; acc1[li] = bb1; }
  const float* w0p = cw + (size_t)e0 * 96;
  const float* w1p = w0p + 96;
  for (int ci = 0; ci < 32; ci++) {
#pragma unroll
    for (int kk = 0; kk < 3; kk++) {
      float w0 = w0p[ci * 3 + kk];
      float w1 = w1p[ci * 3 + kk];
#pragma unroll
      for (int li = 0; li < 8; li++) {
        float xv = xs[li + kk][ci];
        acc0[li] += xv * w0;
        acc1[li] += xv * w1;
      }
    }
  }
  float dv = __expf((float)e0 * (-9.210340371976184f / 512.0f));
#pragma unroll
  for (int li = 0; li < 8; li++) {
    int l = l0 + li;
    float arg = (float)l * dv;
    float sv = __sinf(arg), cv = __cosf(arg);   // native v_sin/v_cos path
    size_t off = ((size_t)b * L + l) * 512 + e0;
    ushort2 ob; ob.x = f2bf(acc0[li] + sv); ob.y = f2bf(acc1[li] + cv);
    *(ushort2*)&outb[off] = ob;
  }
}

// ---------------- bf16 MFMA GEMM, 2-phase pipelined, counted vmcnt (T4) ------
// Y[M,N] = X[M,512] @ W[N,512]^T + bias.  Tile 128 x (NFR*32).
// EPI 0: Yb bf16 (QSCALE: cols<512 prescaled).  EPI 1: Yb bf16 = +R(bf16).
// EPI 2: SiLU->Yb.  EPI 3: Yf f32 (no residual).
// VOUT: n-blocks with n0>=1024 write TRANSPOSED into VT[32][64][2048] (V path).
// VOUT copy indexing is generic in BN (r23: qkv runs NFR=2 for 3 blocks/CU).
template<int EPI, int QSCALE, int NFR, int VOUT>
__global__ __launch_bounds__(256) void gemm_bf(
    const unsigned short* __restrict__ X,
    const unsigned short* __restrict__ W,
    const float* __restrict__ bias,
    const unsigned short* __restrict__ R,
    unsigned short* __restrict__ Yb,
    float* __restrict__ Yf,
    unsigned short* __restrict__ VT,
    int N)
{
  const int K = 512;
  constexpr int BN = NFR * 32;
  constexpr int WB = NFR * 4096;          // W-region bytes per buffer
  constexpr int BUF = 16384 + WB;
  __shared__ __align__(16) char smem[2 * BUF];
  int t = threadIdx.x;
  int lane = t & 63, wv = t >> 6;
  int g = lane >> 4, li = lane & 15;
  int m0 = (blockIdx.x & 63) << 7;
  int n0 = (blockIdx.x >> 6) * BN;
  int wm = (wv >> 1) << 6;
  int wn = (wv & 1) * (BN / 2);

  int subrow = lane >> 3;
  int coloff = ((lane & 7) ^ subrow) << 3;   // inverse swizzle on global source

  f32x4 acc[4][NFR];
#pragma unroll
  for (int a = 0; a < 4; a++)
#pragma unroll
    for (int b2 = 0; b2 < NFR; b2++) acc[a][b2] = (f32x4){0.f, 0.f, 0.f, 0.f};

  // prologue: stage k-step 0 into buf 0 (no drain: first-iter vmcnt covers it)
#pragma unroll
  for (int j = 0; j < 4; j++) {
    int row = (wv * 4 + j) * 8 + subrow;
    gload16(X + (size_t)(m0 + row) * K + coloff,
            (unsigned short*)(smem + (wv * 4 + j) * 1024));
  }
#pragma unroll
  for (int j = 0; j < NFR; j++) {
    int row = (wv * NFR + j) * 8 + subrow;
    gload16(W + (size_t)(n0 + row) * K + coloff,
            (unsigned short*)(smem + 16384 + (wv * NFR + j) * 1024));
  }

#pragma unroll
  for (int ks = 0; ks < 8; ks++) {
    const int buf = ks & 1;
    char* cur = smem + buf * BUF;
    if (ks < 7) {                     // issue next-tile loads first
      char* nxt = smem + (buf ^ 1) * BUF;
      int k0 = (ks + 1) * 64;
#pragma unroll
      for (int j = 0; j < 4; j++) {
        int row = (wv * 4 + j) * 8 + subrow;
        gload16(X + (size_t)(m0 + row) * K + k0 + coloff,
                (unsigned short*)(nxt + (wv * 4 + j) * 1024));
      }
#pragma unroll
      for (int j = 0; j < NFR; j++) {
        int row = (wv * NFR + j) * 8 + subrow;
        gload16(W + (size_t)(n0 + row) * K + k0 + coloff,
                (unsigned short*)(nxt + 16384 + (wv * NFR + j) * 1024));
      }
      // counted wait: only tile-ks loads (oldest) must land; next tile's stay in flight
      if constexpr (NFR == 4) asm volatile("s_waitcnt vmcnt(8)" ::: "memory");
      else if constexpr (NFR == 2) asm volatile("s_waitcnt vmcnt(6)" ::: "memory");
      else asm volatile("s_waitcnt vmcnt(5)" ::: "memory");
    } else {
      asm volatile("s_waitcnt vmcnt(0)" ::: "memory");
    }
    __builtin_amdgcn_s_barrier();          // all waves' tile-ks data visible
    __builtin_amdgcn_sched_barrier(0);

#pragma unroll
    for (int s = 0; s < 2; s++) {
      bf16x8 af[4], bfr[NFR];
#pragma unroll
      for (int mt = 0; mt < 4; mt++) {
        int row = wm + 16 * mt + li;
        af[mt] = *(const bf16x8*)(cur + (row * 8 + ((g + 4 * s) ^ (row & 7))) * 16);
      }
#pragma unroll
      for (int nt = 0; nt < NFR; nt++) {
        int row = wn + 16 * nt + li;
        bfr[nt] = *(const bf16x8*)(cur + 16384 +
                                   (row * 8 + ((g + 4 * s) ^ (row & 7))) * 16);
      }
#pragma unroll
      for (int mt = 0; mt < 4; mt++)
#pragma unroll
        for (int nt = 0; nt < NFR; nt++)
          acc[mt][nt] = __builtin_amdgcn_mfma_f32_16x16x32_bf16(
              af[mt], bfr[nt], acc[mt][nt], 0, 0, 0);
    }
    if (ks < 7) bar_only();                // guard buffer overwrite by iter ks+1's issues
  }

  float bv[NFR];
#pragma unroll
  for (int nt = 0; nt < NFR; nt++) bv[nt] = bias[n0 + wn + 16 * nt + li];

  if (VOUT && n0 >= 1024) {
    // transposed V output: LDS bounce (rows = tile cols, stride 136 shorts)
    unsigned short* Ts = (unsigned short*)smem;
    __builtin_amdgcn_s_barrier();          // all compute reads of smem done
#pragma unroll
    for (int nt = 0; nt < NFR; nt++) {
      int col = wn + 16 * nt + li;
      float bvn = bv[nt];
#pragma unroll
      for (int mt = 0; mt < 4; mt++) {
        float v0 = acc[mt][nt][0] + bvn, v1 = acc[mt][nt][1] + bvn;
        float v2 = acc[mt][nt][2] + bvn, v3 = acc[mt][nt][3] + bvn;
        uint2 pk;
        asm("v_cvt_pk_bf16_f32 %0, %1, %2" : "=v"(pk.x) : "v"(v0), "v"(v1));
        asm("v_cvt_pk_bf16_f32 %0, %1, %2" : "=v"(pk.y) : "v"(v2), "v"(v3));
        *(uint2*)(Ts + col * 136 + wm + 16 * mt + 4 * g) = pk;
      }
    }
    __syncthreads();
    constexpr int TPC = 256 / BN;          // threads per column
    constexpr int CH  = 128 / TPC;         // shorts per thread chunk
    int vcol = t / TPC, sub = t % TPC;
    int gc = n0 - 1024 + vcol;
    int bh = (m0 >> 11) * 8 + (gc >> 6);
    int d  = gc & 63;
    unsigned short* dst = VT + ((size_t)bh * 64 + d) * 2048 + (m0 & 2047) + sub * CH;
    const unsigned short* srcp = Ts + vcol * 136 + sub * CH;
#pragma unroll
    for (int j2 = 0; j2 < CH / 8; j2++)
      *(bf16x8*)(dst + j2 * 8) = *(const bf16x8*)(srcp + j2 * 8);
    return;
  }

#pragma unroll
  for (int mt = 0; mt < 4; mt++) {
#pragma unroll
    for (int i = 0; i < 4; i++) {
      size_t roff = (size_t)(m0 + wm + 16 * mt + 4 * g + i) * N;
#pragma unroll
      for (int nt = 0; nt < NFR; nt++) {
        int col = n0 + wn + 16 * nt + li;
        float v = acc[mt][nt][i] + bv[nt];
        if (EPI == 1) {
          v += bf2f(R[roff + col]);
          Yb[roff + col] = f2bf(v);
        } else if (EPI == 2) {
          v = v / (1.f + __expf(-v));
          Yb[roff + col] = f2bf(v);
        } else if (EPI == 3) {
          Yf[roff + col] = v;
        } else {
          if (QSCALE && col < 512) v *= 0.18033688011112042f;  // 0.125*log2(e)
          Yb[roff + col] = f2bf(v);
        }
      }
    }
  }
}

// ---------------- MFMA flash attention: in-register P, per-chunk schedule ----
// QBLK=128, KVBLK=128; grid 512: bh = bid&31 (XCD-local), qi = bid>>5; 4 waves.
// Q prescaled by 0.125*log2(e); NO-MAX softmax (p = 2^s directly).
// K-row permutation: frag loads K rows 8*(r>>2)+(r&3)+4*odd+32*c so lane holds
// scores for keys 32c+8g+j, q=li == PV A-frag layout; P never touches LDS.
// Per-chunk c: QK(8 mfma) -> exp/pack -> PV(8 mfma) bounds live registers.
// l via ONES-MFMA: accL = mfma(paP, ones, accL) — rowsum lands at the exact
// lane/slot the epilogue needs; no cross-lane l machinery.
__global__ __launch_bounds__(256) void attn_mfma(
    const unsigned short* __restrict__ qkv,  // [8192,1536] bf16
    const unsigned short* __restrict__ Vt,   // [32,64,2048] bf16
    unsigned short* __restrict__ ctx)        // [8192,512] bf16
{
  const int L = 2048;
  int bh = blockIdx.x & 31, qi = blockIdx.x >> 5;   // same-bh blocks -> same XCD
  int b = bh >> 3, h = bh & 7;
  int q0 = qi << 7;
  size_t tb = (size_t)b * L;
  int t = threadIdx.x, lane = t & 63, wv = t >> 6;
  int g = lane >> 4, li = lane & 15;
  int lisw7 = li & 7;

  // smem: buf{0,1}: [K 16K | V 16K] at 0/32768  (no P region)
  __shared__ __align__(16) char smem[65536];

  bf16x8 ones;
#pragma unroll
  for (int j = 0; j < 8; j++) ones[j] = (short)0x3F80;   // bf16 1.0

  int wq = q0 + wv * 32;
  bf16x8 qf00, qf01, qf10, qf11;
  {
    const unsigned short* qp0 = qkv + (tb + wq + li) * 1536 + h * 64 + g * 8;
    qf00 = *(const bf16x8*)qp0;
    qf01 = *(const bf16x8*)(qp0 + 32);
    const unsigned short* qp1 = qp0 + (size_t)16 * 1536;
    qf10 = *(const bf16x8*)qp1;
    qf11 = *(const bf16x8*)(qp1 + 32);
  }

  f32x4 accA[4], accB[4], accLA, accLB;
#pragma unroll
  for (int nt = 0; nt < 4; nt++) {
    accA[nt] = (f32x4){0.f, 0.f, 0.f, 0.f};
    accB[nt] = (f32x4){0.f, 0.f, 0.f, 0.f};
  }
  accLA = (f32x4){0.f, 0.f, 0.f, 0.f};
  accLB = (f32x4){0.f, 0.f, 0.f, 0.f};

  // K read offsets: permuted rows, swizzle key (row>>2)&7
  int rowE = ((li >> 2) << 3) + (li & 3);
  int swzE = (li >> 2) << 1;           // (rowE>>2)&7
  int swzO = swzE + 1;                 // ((rowE+4)>>2)&7
  int kE0 = rowE * 128 + ((g ^ swzE) << 4);
  int kE1 = rowE * 128 + (((g + 4) ^ swzE) << 4);
  int kO0 = (rowE + 4) * 128 + ((g ^ swzO) << 4);
  int kO1 = (rowE + 4) * 128 + (((g + 4) ^ swzO) << 4);
  // V fragment offsets (V region rows = 256B, 16 slots): row = 16nt+li, key ^(row&7)
  int vrowb = 16384 + li * 256;
  int vsl[4];
#pragma unroll
  for (int c = 0; c < 4; c++) vsl[c] = ((g + 4 * c) ^ lisw7) << 4;

  // staging pointers: K swizzle key (2j + subrow>>2)&7 ; V swizzle key row&7
  int subrow = lane >> 3;
  const unsigned short* kp[4];
  const unsigned short* vp[4];
#pragma unroll
  for (int j = 0; j < 4; j++) {
    int krow = (wv * 4 + j) * 8 + subrow;
    int swzk = (2 * j + (subrow >> 2)) & 7;
    kp[j] = qkv + (tb + krow) * 1536 + 512 + h * 64 + (((lane & 7) ^ swzk) << 3);
    int vrow = (wv * 4 + j) * 4 + g;
    vp[j] = Vt + ((size_t)bh * 64 + vrow) * 2048 + ((li ^ (vrow & 7)) << 3);
  }

  // prologue: stage tile 0 into buf 0
#pragma unroll
  for (int j = 0; j < 4; j++) {
    gload16(kp[j], (unsigned short*)(smem + (wv * 4 + j) * 1024));
    gload16(vp[j], (unsigned short*)(smem + 16384 + (wv * 4 + j) * 1024));
    kp[j] += (size_t)128 * 1536; vp[j] += 128;
  }
  pipe_sync();

#pragma unroll 2
  for (int it = 0; it < 16; it++) {
    const int buf = it & 1;
    const char* base = smem + buf * 32768;
    if (it < 15) {                    // issue next tile first (latency hides)
      char* nb = smem + (buf ^ 1) * 32768;
#pragma unroll
      for (int j = 0; j < 4; j++) {
        gload16(kp[j], (unsigned short*)(nb + (wv * 4 + j) * 1024));
        gload16(vp[j], (unsigned short*)(nb + 16384 + (wv * 4 + j) * 1024));
        kp[j] += (size_t)128 * 1536; vp[j] += 128;
      }
    }

    const f32x4 kZ = {0.f, 0.f, 0.f, 0.f};
#pragma unroll
    for (int c = 0; c < 4; c++) {
      const char* cb_ = base + c * 4096;
      // QK: 8 MFMA -> this chunk's scores (keys 32c+8g+0..7, q=li)
      bf16x8 k0 = *(const bf16x8*)(cb_ + kE0);
      bf16x8 k1 = *(const bf16x8*)(cb_ + kE1);
      bf16x8 k2 = *(const bf16x8*)(cb_ + kO0);
      bf16x8 k3 = *(const bf16x8*)(cb_ + kO1);
      __builtin_amdgcn_s_setprio(1);
      f32x4 sEA = __builtin_amdgcn_mfma_f32_16x16x32_bf16(k0, qf00, kZ, 0, 0, 0);
      f32x4 sEB = __builtin_amdgcn_mfma_f32_16x16x32_bf16(k0, qf10, kZ, 0, 0, 0);
      f32x4 sOA = __builtin_amdgcn_mfma_f32_16x16x32_bf16(k2, qf00, kZ, 0, 0, 0);
      f32x4 sOB = __builtin_amdgcn_mfma_f32_16x16x32_bf16(k2, qf10, kZ, 0, 0, 0);
      sEA = __builtin_amdgcn_mfma_f32_16x16x32_bf16(k1, qf01, sEA, 0, 0, 0);
      sEB = __builtin_amdgcn_mfma_f32_16x16x32_bf16(k1, qf11, sEB, 0, 0, 0);
      sOA = __builtin_amdgcn_mfma_f32_16x16x32_bf16(k3, qf01, sOA, 0, 0, 0);
      sOB = __builtin_amdgcn_mfma_f32_16x16x32_bf16(k3, qf11, sOB, 0, 0, 0);
      __builtin_amdgcn_s_setprio(0);

      // exp + pack straight into PV A-fragments (registers only)
      bf16x8 paA, paB;
#define EPACK(SE, SO, PA)                                                     \
      {                                                                       \
        float e0 = SE[0], e1 = SE[1], e2 = SE[2], e3 = SE[3];                 \
        float o0 = SO[0], o1 = SO[1], o2 = SO[2], o3 = SO[3];                 \
        asm volatile("v_exp_f32 %0, %0\n\tv_exp_f32 %1, %1\n\t"               \
                     "v_exp_f32 %2, %2\n\tv_exp_f32 %3, %3\n\ts_nop 1"        \
                     : "+v"(e0), "+v"(e1), "+v"(e2), "+v"(e3));               \
        asm volatile("v_exp_f32 %0, %0\n\tv_exp_f32 %1, %1\n\t"               \
                     "v_exp_f32 %2, %2\n\tv_exp_f32 %3, %3\n\ts_nop 1"        \
                     : "+v"(o0), "+v"(o1), "+v"(o2), "+v"(o3));               \
        unsigned int d0, d1, d2, d3;                                          \
        asm("v_cvt_pk_bf16_f32 %0, %1, %2" : "=v"(d0) : "v"(e0), "v"(e1));    \
        asm("v_cvt_pk_bf16_f32 %0, %1, %2" : "=v"(d1) : "v"(e2), "v"(e3));    \
        asm("v_cvt_pk_bf16_f32 %0, %1, %2" : "=v"(d2) : "v"(o0), "v"(o1));    \
        asm("v_cvt_pk_bf16_f32 %0, %1, %2" : "=v"(d3) : "v"(o2), "v"(o3));    \
        unsigned int tmp_[4] = {d0, d1, d2, d3};                              \
        __builtin_memcpy(&PA, tmp_, 16);                                      \
      }
      EPACK(sEA, sOA, paA)
      EPACK(sEB, sOB, paB)
#undef EPACK

      // PV: 8 MFMA for this chunk + 2 l-MFMAs (rowsum via ones B-operand)
      __builtin_amdgcn_s_setprio(1);
#pragma unroll
      for (int nt = 0; nt < 4; nt++) {
        bf16x8 vb = *(const bf16x8*)(base + vrowb + nt * 4096 + vsl[c]);
        accA[nt] = __builtin_amdgcn_mfma_f32_16x16x32_bf16(paA, vb, accA[nt], 0, 0, 0);
        accB[nt] = __builtin_amdgcn_mfma_f32_16x16x32_bf16(paB, vb, accB[nt], 0, 0, 0);
      }
      accLA = __builtin_amdgcn_mfma_f32_16x16x32_bf16(paA, ones, accLA, 0, 0, 0);
      accLB = __builtin_amdgcn_mfma_f32_16x16x32_bf16(paB, ones, accLB, 0, 0, 0);
      __builtin_amdgcn_s_setprio(0);
    }

    pipe_sync();
  }

  // accLA[i] = l for q-row wq+4g+i; no cross-lane needed.
  float liA[4], liB[4];
#pragma unroll
  for (int i = 0; i < 4; i++) {
    liA[i] = 1.f / accLA[i];
    liB[i] = 1.f / accLB[i];
  }
#pragma unroll
  for (int i = 0; i < 4; i++) {
    size_t ra = (tb + wq + 4 * g + i) * 512 + h * 64;
    size_t rb = (tb + wq + 16 + 4 * g + i) * 512 + h * 64;
#pragma unroll
    for (int nt = 0; nt < 4; nt++) {
      ctx[ra + 16 * nt + li] = f2bf(accA[nt][i] * liA[i]);
      ctx[rb + 16 * nt + li] = f2bf(accB[nt][i] * liB[i]);
    }
  }
}

// ---------------- LayerNorm over E=512 (bf16 in, bf16 out); one wave/row -----
__global__ __launch_bounds__(256) void ln_kernel(
    const unsigned short* __restrict__ X, const float* __restrict__ g,
    const float* __restrict__ b, unsigned short* __restrict__ Yb)
{
  int t = threadIdx.x, lane = t & 63, wv = t >> 6;
  size_t row = (size_t)blockIdx.x * 4 + wv;
  bf16x8 xv = *(const bf16x8*)(X + row * 512 + lane * 8);
  float xf[8];
#pragma unroll
  for (int j = 0; j < 8; j++) xf[j] = bf2f((unsigned short)xv[j]);
  float sum = 0.f, sq = 0.f;
#pragma unroll
  for (int j = 0; j < 8; j++) { sum += xf[j]; sq += xf[j] * xf[j]; }
#pragma unroll
  for (int off = 32; off > 0; off >>= 1) {
    sum += __shfl_xor(sum, off);
    sq  += __shfl_xor(sq, off);
  }
  float mu  = sum * (1.0f / 512.0f);
  float inv = rsqrtf(sq * (1.0f / 512.0f) - mu * mu + 1e-5f);
  float4 g0 = *(const float4*)(g + lane * 8);
  float4 g1 = *(const float4*)(g + lane * 8 + 4);
  float4 b0 = *(const float4*)(b + lane * 8);
  float4 b1 = *(const float4*)(b + lane * 8 + 4);
  float gw[8] = {g0.x, g0.y, g0.z, g0.w, g1.x, g1.y, g1.z, g1.w};
  float bw[8] = {b0.x, b0.y, b0.z, b0.w, b1.x, b1.y, b1.z, b1.w};
  bf16x8 yb;
#pragma unroll
  for (int j = 0; j < 8; j++)
    yb[j] = (short)f2bf((xf[j] - mu) * inv * gw[j] + bw[j]);
  *(bf16x8*)(Yb + row * 512 + lane * 8) = yb;
}

extern "C" void kernel_launch(void* const* d_in, const int* in_sizes, int n_in,
                              void* d_out, int out_size, void* d_ws, size_t ws_size,
                              hipStream_t stream) {
  (void)in_sizes; (void)n_in; (void)out_size; (void)ws_size;
  const float* x      = (const float*)d_in[0];
  const float* conv_w = (const float*)d_in[1];
  const float* conv_b = (const float*)d_in[2];
  const float* qkv_w  = (const float*)d_in[3];
  const float* qkv_b  = (const float*)d_in[4];
  const float* out_w  = (const float*)d_in[5];
  const float* out_b  = (const float*)d_in[6];
  const float* fc1_w  = (const float*)d_in[7];
  const float* fc1_b  = (const float*)d_in[8];
  const float* fc2_w  = (const float*)d_in[9];
  const float* fc2_b  = (const float*)d_in[10];
  const float* ln1_w  = (const float*)d_in[11];
  const float* ln1_b  = (const float*)d_in[12];
  const float* ln2_w  = (const float*)d_in[13];
  const float* ln2_b  = (const float*)d_in[14];
  const float* outp_w = (const float*)d_in[15];
  const float* outp_b = (const float*)d_in[16];
  float* out = (float*)d_out;

  char* p = (char*)d_ws;
  unsigned short* A    = (unsigned short*)p;            p += (size_t)8192 * 512 * 2;
  unsigned short* QKV  = (unsigned short*)p;            p += (size_t)8192 * 1536 * 2;
  unsigned short* VT   = (unsigned short*)p;            p += (size_t)32 * 64 * 2048 * 2;
  unsigned short* CTX  = (unsigned short*)p;            p += (size_t)8192 * 512 * 2;
  unsigned short* Wq   = (unsigned short*)p;            p += (size_t)4 * 1536 * 512 * 2;
  unsigned short* Wo   = (unsigned short*)p;            p += (size_t)4 * 512 * 512 * 2;
  unsigned short* W1   = (unsigned short*)p;            p += (size_t)4 * 512 * 512 * 2;
  unsigned short* W2   = (unsigned short*)p;            p += (size_t)4 * 512 * 512 * 2;
  unsigned short* Wp   = (unsigned short*)p;            p += (size_t)32 * 512 * 2;
  unsigned short* D = QKV;   // aliased: D[8192,512] bf16 in QKV region (disjoint lifetime)

  cvt_all<<<6160, 256, 0, stream>>>(qkv_w, out_w, fc1_w, fc2_w, outp_w, Wq);

  conv_pe_kernel<<<1024, 256, 0, stream>>>(x, conv_w, conv_b, A);

  for (int l = 0; l < 4; l++) {
    gemm_bf<0, 1, 2, 1><<<64 * 24, 256, 0, stream>>>(
        A, Wq + (size_t)l * 1536 * 512, qkv_b + l * 1536, nullptr,
        QKV, nullptr, VT, 1536);
    attn_mfma<<<512, 256, 0, stream>>>(QKV, VT, CTX);
    gemm_bf<1, 0, 2, 0><<<64 * 8, 256, 0, stream>>>(
        CTX, Wo + (size_t)l * 512 * 512, out_b + l * 512, A,
        D, nullptr, nullptr, 512);
    ln_kernel<<<2048, 256, 0, stream>>>(D, ln1_w + l * 512, ln1_b + l * 512, A);
    gemm_bf<2, 0, 2, 0><<<64 * 8, 256, 0, stream>>>(
        A, W1 + (size_t)l * 512 * 512, fc1_b + l * 512, nullptr,
        CTX, nullptr, nullptr, 512);
    gemm_bf<1, 0, 2, 0><<<64 * 8, 256, 0, stream>>>(
        CTX, W2 + (size_t)l * 512 * 512, fc2_b + l * 512, A,
        D, nullptr, nullptr, 512);
    ln_kernel<<<2048, 256, 0, stream>>>(D, ln2_w + l * 512, ln2_b + l * 512, A);
  }
  gemm_bf<3, 0, 1, 0><<<64, 256, 0, stream>>>(
      A, Wp, outp_b, nullptr, nullptr, out, nullptr, 32);
}

// Round 24
// 454.430 us; speedup vs baseline: 1.0034x; 1.0034x over previous
//
#include <hip/hip_runtime.h>
#include <hip/hip_bf16.h>
#include <cstddef>

typedef short bf16x8 __attribute__((ext_vector_type(8)));
typedef float f32x4 __attribute__((ext_vector_type(4)));

__device__ __forceinline__ unsigned short f2bf(float x) {
  __hip_bfloat16 h = __float2bfloat16(x);
  unsigned short u; __builtin_memcpy(&u, &h, 2); return u;
}
__device__ __forceinline__ float bf2f(unsigned short u) {
  unsigned int v = ((unsigned int)u) << 16; float f; __builtin_memcpy(&f, &v, 4); return f;
}
__device__ __forceinline__ void gload16(const unsigned short* g, unsigned short* l) {
  __builtin_amdgcn_global_load_lds(
      (const __attribute__((address_space(1))) void*)g,
      (__attribute__((address_space(3))) void*)l, 16, 0, 0);
}
__device__ __forceinline__ void pipe_sync() {
  asm volatile("s_waitcnt vmcnt(0)" ::: "memory");
  __builtin_amdgcn_s_barrier();
  __builtin_amdgcn_sched_barrier(0);
}
__device__ __forceinline__ void bar_only() {
  asm volatile("" ::: "memory");
  __builtin_amdgcn_s_barrier();
  __builtin_amdgcn_sched_barrier(0);
}

// ---------------- all weights fp32 -> bf16 (contiguous dst) ----------------
__global__ __launch_bounds__(256) void cvt_all(
    const float* __restrict__ qkv_w, const float* __restrict__ out_w,
    const float* __restrict__ fc1_w, const float* __restrict__ fc2_w,
    const float* __restrict__ outp_w, unsigned short* __restrict__ dst)
{
  int i = blockIdx.x * 256 + threadIdx.x;
  if (i >= 1576960) return;
  const float* src; int off;
  if (i < 786432)       { src = qkv_w;  off = i; }
  else if (i < 1048576) { src = out_w;  off = i - 786432; }
  else if (i < 1310720) { src = fc1_w;  off = i - 1048576; }
  else if (i < 1572864) { src = fc2_w;  off = i - 1310720; }
  else                  { src = outp_w; off = i - 1572864; }
  float4 v = *(const float4*)(src + (size_t)off * 4);
  ushort4 o;
  o.x = f2bf(v.x); o.y = f2bf(v.y); o.z = f2bf(v.z); o.w = f2bf(v.w);
  *(ushort4*)(dst + (size_t)i * 4) = o;
}

// ---------------- conv1d (circular, k=3) + positional embedding -> bf16 ------
__global__ __launch_bounds__(256) void conv_pe_kernel(
    const float* __restrict__ x, const float* __restrict__ cw,
    const float* __restrict__ cb, unsigned short* __restrict__ outb)
{
  const int L = 2048, CIN = 32;
  int b  = blockIdx.x >> 8;
  int l0 = (blockIdx.x & 255) << 3;
  int t  = threadIdx.x;
  __shared__ float xs[10][32];
  for (int idx = t; idx < 320; idx += 256) {
    int rr = idx >> 5, ci = idx & 31;
    int gl = (l0 - 1 + rr + L) & (L - 1);
    xs[rr][ci] = x[((size_t)b * L + gl) * CIN + ci];
  }
  __syncthreads();
  int e0 = t << 1;
  float acc0[8], acc1[8];
  float bb0 = cb[e0], bb1 = cb[e0 + 1];
#pragma unroll
  for (int li = 0; li < 8; li++) { acc0[li] = bb0; acc1[li] = bb1; }
  const float* w0p = cw + (size_t)e0 * 96;
  const float* w1p = w0p + 96;
  for (int ci = 0; ci < 32; ci++) {
#pragma unroll
    for (int kk = 0; kk < 3; kk++) {
      float w0 = w0p[ci * 3 + kk];
      float w1 = w1p[ci * 3 + kk];
#pragma unroll
      for (int li = 0; li < 8; li++) {
        float xv = xs[li + kk][ci];
        acc0[li] += xv * w0;
        acc1[li] += xv * w1;
      }
    }
  }
  float dv = __expf((float)e0 * (-9.210340371976184f / 512.0f));
#pragma unroll
  for (int li = 0; li < 8; li++) {
    int l = l0 + li;
    float arg = (float)l * dv;
    float sv = __sinf(arg), cv = __cosf(arg);   // native v_sin/v_cos path
    size_t off = ((size_t)b * L + l) * 512 + e0;
    ushort2 ob; ob.x = f2bf(acc0[li] + sv); ob.y = f2bf(acc1[li] + cv);
    *(ushort2*)&outb[off] = ob;
  }
}

// ---------------- bf16 MFMA GEMM, 2-phase pipelined, counted vmcnt (T4) ------
// Y[M,N] = X[M,512] @ W[N,512]^T + bias.  Tile 128 x (NFR*32).
// EPI 0: Yb bf16 (QSCALE: cols<512 prescaled).  EPI 1: Yb bf16 = +R(bf16).
// EPI 2: SiLU->Yb.  EPI 3: Yf f32 (no residual).
// VOUT: n-blocks with n0>=1024 write TRANSPOSED into VT[32][64][2048] (V path).
template<int EPI, int QSCALE, int NFR, int VOUT>
__global__ __launch_bounds__(256) void gemm_bf(
    const unsigned short* __restrict__ X,
    const unsigned short* __restrict__ W,
    const float* __restrict__ bias,
    const unsigned short* __restrict__ R,
    unsigned short* __restrict__ Yb,
    float* __restrict__ Yf,
    unsigned short* __restrict__ VT,
    int N)
{
  const int K = 512;
  constexpr int BN = NFR * 32;
  constexpr int WB = NFR * 4096;          // W-region bytes per buffer
  constexpr int BUF = 16384 + WB;
  __shared__ __align__(16) char smem[2 * BUF];
  int t = threadIdx.x;
  int lane = t & 63, wv = t >> 6;
  int g = lane >> 4, li = lane & 15;
  int m0 = (blockIdx.x & 63) << 7;
  int n0 = (blockIdx.x >> 6) * BN;
  int wm = (wv >> 1) << 6;
  int wn = (wv & 1) * (BN / 2);

  int subrow = lane >> 3;
  int coloff = ((lane & 7) ^ subrow) << 3;   // inverse swizzle on global source

  f32x4 acc[4][NFR];
#pragma unroll
  for (int a = 0; a < 4; a++)
#pragma unroll
    for (int b2 = 0; b2 < NFR; b2++) acc[a][b2] = (f32x4){0.f, 0.f, 0.f, 0.f};

  // prologue: stage k-step 0 into buf 0 (no drain: first-iter vmcnt covers it)
#pragma unroll
  for (int j = 0; j < 4; j++) {
    int row = (wv * 4 + j) * 8 + subrow;
    gload16(X + (size_t)(m0 + row) * K + coloff,
            (unsigned short*)(smem + (wv * 4 + j) * 1024));
  }
#pragma unroll
  for (int j = 0; j < NFR; j++) {
    int row = (wv * NFR + j) * 8 + subrow;
    gload16(W + (size_t)(n0 + row) * K + coloff,
            (unsigned short*)(smem + 16384 + (wv * NFR + j) * 1024));
  }

#pragma unroll
  for (int ks = 0; ks < 8; ks++) {
    const int buf = ks & 1;
    char* cur = smem + buf * BUF;
    if (ks < 7) {                     // issue next-tile loads first
      char* nxt = smem + (buf ^ 1) * BUF;
      int k0 = (ks + 1) * 64;
#pragma unroll
      for (int j = 0; j < 4; j++) {
        int row = (wv * 4 + j) * 8 + subrow;
        gload16(X + (size_t)(m0 + row) * K + k0 + coloff,
                (unsigned short*)(nxt + (wv * 4 + j) * 1024));
      }
#pragma unroll
      for (int j = 0; j < NFR; j++) {
        int row = (wv * NFR + j) * 8 + subrow;
        gload16(W + (size_t)(n0 + row) * K + k0 + coloff,
                (unsigned short*)(nxt + 16384 + (wv * NFR + j) * 1024));
      }
      // counted wait: only tile-ks loads (oldest) must land; next tile's stay in flight
      if constexpr (NFR == 4) asm volatile("s_waitcnt vmcnt(8)" ::: "memory");
      else if constexpr (NFR == 2) asm volatile("s_waitcnt vmcnt(6)" ::: "memory");
      else asm volatile("s_waitcnt vmcnt(5)" ::: "memory");
    } else {
      asm volatile("s_waitcnt vmcnt(0)" ::: "memory");
    }
    __builtin_amdgcn_s_barrier();          // all waves' tile-ks data visible
    __builtin_amdgcn_sched_barrier(0);

#pragma unroll
    for (int s = 0; s < 2; s++) {
      bf16x8 af[4], bfr[NFR];
#pragma unroll
      for (int mt = 0; mt < 4; mt++) {
        int row = wm + 16 * mt + li;
        af[mt] = *(const bf16x8*)(cur + (row * 8 + ((g + 4 * s) ^ (row & 7))) * 16);
      }
#pragma unroll
      for (int nt = 0; nt < NFR; nt++) {
        int row = wn + 16 * nt + li;
        bfr[nt] = *(const bf16x8*)(cur + 16384 +
                                   (row * 8 + ((g + 4 * s) ^ (row & 7))) * 16);
      }
#pragma unroll
      for (int mt = 0; mt < 4; mt++)
#pragma unroll
        for (int nt = 0; nt < NFR; nt++)
          acc[mt][nt] = __builtin_amdgcn_mfma_f32_16x16x32_bf16(
              af[mt], bfr[nt], acc[mt][nt], 0, 0, 0);
    }
    if (ks < 7) bar_only();                // guard buffer overwrite by iter ks+1's issues
  }

  float bv[NFR];
#pragma unroll
  for (int nt = 0; nt < NFR; nt++) bv[nt] = bias[n0 + wn + 16 * nt + li];

  if (VOUT && n0 >= 1024) {
    // transposed V output: LDS bounce (rows = tile cols, stride 136 shorts)
    unsigned short* Ts = (unsigned short*)smem;
    __builtin_amdgcn_s_barrier();          // all compute reads of smem done
#pragma unroll
    for (int nt = 0; nt < NFR; nt++) {
      int col = wn + 16 * nt + li;
      float bvn = bv[nt];
#pragma unroll
      for (int mt = 0; mt < 4; mt++) {
        float v0 = acc[mt][nt][0] + bvn, v1 = acc[mt][nt][1] + bvn;
        float v2 = acc[mt][nt][2] + bvn, v3 = acc[mt][nt][3] + bvn;
        uint2 pk;
        asm("v_cvt_pk_bf16_f32 %0, %1, %2" : "=v"(pk.x) : "v"(v0), "v"(v1));
        asm("v_cvt_pk_bf16_f32 %0, %1, %2" : "=v"(pk.y) : "v"(v2), "v"(v3));
        *(uint2*)(Ts + col * 136 + wm + 16 * mt + 4 * g) = pk;
      }
    }
    __syncthreads();
    constexpr int TPC = 256 / BN;          // threads per column
    constexpr int CH  = 128 / TPC;         // shorts per thread chunk
    int vcol = t / TPC, sub = t % TPC;
    int gc = n0 - 1024 + vcol;
    int bh = (m0 >> 11) * 8 + (gc >> 6);
    int d  = gc & 63;
    unsigned short* dst = VT + ((size_t)bh * 64 + d) * 2048 + (m0 & 2047) + sub * CH;
    const unsigned short* srcp = Ts + vcol * 136 + sub * CH;
#pragma unroll
    for (int j2 = 0; j2 < CH / 8; j2++)
      *(bf16x8*)(dst + j2 * 8) = *(const bf16x8*)(srcp + j2 * 8);
    return;
  }

#pragma unroll
  for (int mt = 0; mt < 4; mt++) {
#pragma unroll
    for (int i = 0; i < 4; i++) {
      size_t roff = (size_t)(m0 + wm + 16 * mt + 4 * g + i) * N;
#pragma unroll
      for (int nt = 0; nt < NFR; nt++) {
        int col = n0 + wn + 16 * nt + li;
        float v = acc[mt][nt][i] + bv[nt];
        if (EPI == 1) {
          v += bf2f(R[roff + col]);
          Yb[roff + col] = f2bf(v);
        } else if (EPI == 2) {
          v = v / (1.f + __expf(-v));
          Yb[roff + col] = f2bf(v);
        } else if (EPI == 3) {
          Yf[roff + col] = v;
        } else {
          if (QSCALE && col < 512) v *= 0.18033688011112042f;  // 0.125*log2(e)
          Yb[roff + col] = f2bf(v);
        }
      }
    }
  }
}

// ---------------- MFMA flash attention: in-register P, per-chunk schedule ----
// QBLK=128, KVBLK=128; grid 512: bh = bid&31 (XCD-local), qi = bid>>5; 4 waves.
// Q prescaled by 0.125*log2(e); NO-MAX softmax (p = 2^s directly).
// K-row permutation: frag loads K rows 8*(r>>2)+(r&3)+4*odd+32*c so lane holds
// scores for keys 32c+8g+j, q=li == PV A-frag layout; P never touches LDS.
// Per-chunk c: QK(8 mfma) -> exp/pack -> PV(8 mfma) bounds live registers.
// l via ONES-MFMA: accL = mfma(paP, ones, accL) — rowsum lands at the exact
// lane/slot the epilogue needs; no cross-lane l machinery.
__global__ __launch_bounds__(256) void attn_mfma(
    const unsigned short* __restrict__ qkv,  // [8192,1536] bf16
    const unsigned short* __restrict__ Vt,   // [32,64,2048] bf16
    unsigned short* __restrict__ ctx)        // [8192,512] bf16
{
  const int L = 2048;
  int bh = blockIdx.x & 31, qi = blockIdx.x >> 5;   // same-bh blocks -> same XCD
  int b = bh >> 3, h = bh & 7;
  int q0 = qi << 7;
  size_t tb = (size_t)b * L;
  int t = threadIdx.x, lane = t & 63, wv = t >> 6;
  int g = lane >> 4, li = lane & 15;
  int lisw7 = li & 7;

  // smem: buf{0,1}: [K 16K | V 16K] at 0/32768  (no P region)
  __shared__ __align__(16) char smem[65536];

  bf16x8 ones;
#pragma unroll
  for (int j = 0; j < 8; j++) ones[j] = (short)0x3F80;   // bf16 1.0

  int wq = q0 + wv * 32;
  bf16x8 qf00, qf01, qf10, qf11;
  {
    const unsigned short* qp0 = qkv + (tb + wq + li) * 1536 + h * 64 + g * 8;
    qf00 = *(const bf16x8*)qp0;
    qf01 = *(const bf16x8*)(qp0 + 32);
    const unsigned short* qp1 = qp0 + (size_t)16 * 1536;
    qf10 = *(const bf16x8*)qp1;
    qf11 = *(const bf16x8*)(qp1 + 32);
  }

  f32x4 accA[4], accB[4], accLA, accLB;
#pragma unroll
  for (int nt = 0; nt < 4; nt++) {
    accA[nt] = (f32x4){0.f, 0.f, 0.f, 0.f};
    accB[nt] = (f32x4){0.f, 0.f, 0.f, 0.f};
  }
  accLA = (f32x4){0.f, 0.f, 0.f, 0.f};
  accLB = (f32x4){0.f, 0.f, 0.f, 0.f};

  // K read offsets: permuted rows, swizzle key (row>>2)&7
  int rowE = ((li >> 2) << 3) + (li & 3);
  int swzE = (li >> 2) << 1;           // (rowE>>2)&7
  int swzO = swzE + 1;                 // ((rowE+4)>>2)&7
  int kE0 = rowE * 128 + ((g ^ swzE) << 4);
  int kE1 = rowE * 128 + (((g + 4) ^ swzE) << 4);
  int kO0 = (rowE + 4) * 128 + ((g ^ swzO) << 4);
  int kO1 = (rowE + 4) * 128 + (((g + 4) ^ swzO) << 4);
  // V fragment offsets (V region rows = 256B, 16 slots): row = 16nt+li, key ^(row&7)
  int vrowb = 16384 + li * 256;
  int vsl[4];
#pragma unroll
  for (int c = 0; c < 4; c++) vsl[c] = ((g + 4 * c) ^ lisw7) << 4;

  // staging pointers: K swizzle key (2j + subrow>>2)&7 ; V swizzle key row&7
  int subrow = lane >> 3;
  const unsigned short* kp[4];
  const unsigned short* vp[4];
#pragma unroll
  for (int j = 0; j < 4; j++) {
    int krow = (wv * 4 + j) * 8 + subrow;
    int swzk = (2 * j + (subrow >> 2)) & 7;
    kp[j] = qkv + (tb + krow) * 1536 + 512 + h * 64 + (((lane & 7) ^ swzk) << 3);
    int vrow = (wv * 4 + j) * 4 + g;
    vp[j] = Vt + ((size_t)bh * 64 + vrow) * 2048 + ((li ^ (vrow & 7)) << 3);
  }

  // prologue: stage tile 0 into buf 0
#pragma unroll
  for (int j = 0; j < 4; j++) {
    gload16(kp[j], (unsigned short*)(smem + (wv * 4 + j) * 1024));
    gload16(vp[j], (unsigned short*)(smem + 16384 + (wv * 4 + j) * 1024));
    kp[j] += (size_t)128 * 1536; vp[j] += 128;
  }
  pipe_sync();

#pragma unroll 2
  for (int it = 0; it < 16; it++) {
    const int buf = it & 1;
    const char* base = smem + buf * 32768;
    if (it < 15) {                    // issue next tile first (latency hides)
      char* nb = smem + (buf ^ 1) * 32768;
#pragma unroll
      for (int j = 0; j < 4; j++) {
        gload16(kp[j], (unsigned short*)(nb + (wv * 4 + j) * 1024));
        gload16(vp[j], (unsigned short*)(nb + 16384 + (wv * 4 + j) * 1024));
        kp[j] += (size_t)128 * 1536; vp[j] += 128;
      }
    }

    const f32x4 kZ = {0.f, 0.f, 0.f, 0.f};
#pragma unroll
    for (int c = 0; c < 4; c++) {
      const char* cb_ = base + c * 4096;
      // QK: 8 MFMA -> this chunk's scores (keys 32c+8g+0..7, q=li)
      bf16x8 k0 = *(const bf16x8*)(cb_ + kE0);
      bf16x8 k1 = *(const bf16x8*)(cb_ + kE1);
      bf16x8 k2 = *(const bf16x8*)(cb_ + kO0);
      bf16x8 k3 = *(const bf16x8*)(cb_ + kO1);
      __builtin_amdgcn_s_setprio(1);
      f32x4 sEA = __builtin_amdgcn_mfma_f32_16x16x32_bf16(k0, qf00, kZ, 0, 0, 0);
      f32x4 sEB = __builtin_amdgcn_mfma_f32_16x16x32_bf16(k0, qf10, kZ, 0, 0, 0);
      f32x4 sOA = __builtin_amdgcn_mfma_f32_16x16x32_bf16(k2, qf00, kZ, 0, 0, 0);
      f32x4 sOB = __builtin_amdgcn_mfma_f32_16x16x32_bf16(k2, qf10, kZ, 0, 0, 0);
      sEA = __builtin_amdgcn_mfma_f32_16x16x32_bf16(k1, qf01, sEA, 0, 0, 0);
      sEB = __builtin_amdgcn_mfma_f32_16x16x32_bf16(k1, qf11, sEB, 0, 0, 0);
      sOA = __builtin_amdgcn_mfma_f32_16x16x32_bf16(k3, qf01, sOA, 0, 0, 0);
      sOB = __builtin_amdgcn_mfma_f32_16x16x32_bf16(k3, qf11, sOB, 0, 0, 0);
      __builtin_amdgcn_s_setprio(0);

      // exp + pack straight into PV A-fragments (registers only)
      bf16x8 paA, paB;
#define EPACK(SE, SO, PA)                                                     \
      {                                                                       \
        float e0 = SE[0], e1 = SE[1], e2 = SE[2], e3 = SE[3];                 \
        float o0 = SO[0], o1 = SO[1], o2 = SO[2], o3 = SO[3];                 \
        asm volatile("v_exp_f32 %0, %0\n\tv_exp_f32 %1, %1\n\t"               \
                     "v_exp_f32 %2, %2\n\tv_exp_f32 %3, %3\n\ts_nop 1"        \
                     : "+v"(e0), "+v"(e1), "+v"(e2), "+v"(e3));               \
        asm volatile("v_exp_f32 %0, %0\n\tv_exp_f32 %1, %1\n\t"               \
                     "v_exp_f32 %2, %2\n\tv_exp_f32 %3, %3\n\ts_nop 1"        \
                     : "+v"(o0), "+v"(o1), "+v"(o2), "+v"(o3));               \
        unsigned int d0, d1, d2, d3;                                          \
        asm("v_cvt_pk_bf16_f32 %0, %1, %2" : "=v"(d0) : "v"(e0), "v"(e1));    \
        asm("v_cvt_pk_bf16_f32 %0, %1, %2" : "=v"(d1) : "v"(e2), "v"(e3));    \
        asm("v_cvt_pk_bf16_f32 %0, %1, %2" : "=v"(d2) : "v"(o0), "v"(o1));    \
        asm("v_cvt_pk_bf16_f32 %0, %1, %2" : "=v"(d3) : "v"(o2), "v"(o3));    \
        unsigned int tmp_[4] = {d0, d1, d2, d3};                              \
        __builtin_memcpy(&PA, tmp_, 16);                                      \
      }
      EPACK(sEA, sOA, paA)
      EPACK(sEB, sOB, paB)
#undef EPACK

      // PV: 8 MFMA for this chunk + 2 l-MFMAs (rowsum via ones B-operand)
      __builtin_amdgcn_s_setprio(1);
#pragma unroll
      for (int nt = 0; nt < 4; nt++) {
        bf16x8 vb = *(const bf16x8*)(base + vrowb + nt * 4096 + vsl[c]);
        accA[nt] = __builtin_amdgcn_mfma_f32_16x16x32_bf16(paA, vb, accA[nt], 0, 0, 0);
        accB[nt] = __builtin_amdgcn_mfma_f32_16x16x32_bf16(paB, vb, accB[nt], 0, 0, 0);
      }
      accLA = __builtin_amdgcn_mfma_f32_16x16x32_bf16(paA, ones, accLA, 0, 0, 0);
      accLB = __builtin_amdgcn_mfma_f32_16x16x32_bf16(paB, ones, accLB, 0, 0, 0);
      __builtin_amdgcn_s_setprio(0);
    }

    pipe_sync();
  }

  // accLA[i] = l for q-row wq+4g+i; no cross-lane needed.
  float liA[4], liB[4];
#pragma unroll
  for (int i = 0; i < 4; i++) {
    liA[i] = 1.f / accLA[i];
    liB[i] = 1.f / accLB[i];
  }
#pragma unroll
  for (int i = 0; i < 4; i++) {
    size_t ra = (tb + wq + 4 * g + i) * 512 + h * 64;
    size_t rb = (tb + wq + 16 + 4 * g + i) * 512 + h * 64;
#pragma unroll
    for (int nt = 0; nt < 4; nt++) {
      ctx[ra + 16 * nt + li] = f2bf(accA[nt][i] * liA[i]);
      ctx[rb + 16 * nt + li] = f2bf(accB[nt][i] * liB[i]);
    }
  }
}

// ---------------- LayerNorm over E=512 (bf16 in, bf16 out); one wave/row -----
__global__ __launch_bounds__(256) void ln_kernel(
    const unsigned short* __restrict__ X, const float* __restrict__ g,
    const float* __restrict__ b, unsigned short* __restrict__ Yb)
{
  int t = threadIdx.x, lane = t & 63, wv = t >> 6;
  size_t row = (size_t)blockIdx.x * 4 + wv;
  bf16x8 xv = *(const bf16x8*)(X + row * 512 + lane * 8);
  float xf[8];
#pragma unroll
  for (int j = 0; j < 8; j++) xf[j] = bf2f((unsigned short)xv[j]);
  float sum = 0.f, sq = 0.f;
#pragma unroll
  for (int j = 0; j < 8; j++) { sum += xf[j]; sq += xf[j] * xf[j]; }
#pragma unroll
  for (int off = 32; off > 0; off >>= 1) {
    sum += __shfl_xor(sum, off);
    sq  += __shfl_xor(sq, off);
  }
  float mu  = sum * (1.0f / 512.0f);
  float inv = rsqrtf(sq * (1.0f / 512.0f) - mu * mu + 1e-5f);
  float4 g0 = *(const float4*)(g + lane * 8);
  float4 g1 = *(const float4*)(g + lane * 8 + 4);
  float4 b0 = *(const float4*)(b + lane * 8);
  float4 b1 = *(const float4*)(b + lane * 8 + 4);
  float gw[8] = {g0.x, g0.y, g0.z, g0.w, g1.x, g1.y, g1.z, g1.w};
  float bw[8] = {b0.x, b0.y, b0.z, b0.w, b1.x, b1.y, b1.z, b1.w};
  bf16x8 yb;
#pragma unroll
  for (int j = 0; j < 8; j++)
    yb[j] = (short)f2bf((xf[j] - mu) * inv * gw[j] + bw[j]);
  *(bf16x8*)(Yb + row * 512 + lane * 8) = yb;
}

extern "C" void kernel_launch(void* const* d_in, const int* in_sizes, int n_in,
                              void* d_out, int out_size, void* d_ws, size_t ws_size,
                              hipStream_t stream) {
  (void)in_sizes; (void)n_in; (void)out_size; (void)ws_size;
  const float* x      = (const float*)d_in[0];
  const float* conv_w = (const float*)d_in[1];
  const float* conv_b = (const float*)d_in[2];
  const float* qkv_w  = (const float*)d_in[3];
  const float* qkv_b  = (const float*)d_in[4];
  const float* out_w  = (const float*)d_in[5];
  const float* out_b  = (const float*)d_in[6];
  const float* fc1_w  = (const float*)d_in[7];
  const float* fc1_b  = (const float*)d_in[8];
  const float* fc2_w  = (const float*)d_in[9];
  const float* fc2_b  = (const float*)d_in[10];
  const float* ln1_w  = (const float*)d_in[11];
  const float* ln1_b  = (const float*)d_in[12];
  const float* ln2_w  = (const float*)d_in[13];
  const float* ln2_b  = (const float*)d_in[14];
  const float* outp_w = (const float*)d_in[15];
  const float* outp_b = (const float*)d_in[16];
  float* out = (float*)d_out;

  char* p = (char*)d_ws;
  unsigned short* A    = (unsigned short*)p;            p += (size_t)8192 * 512 * 2;
  unsigned short* QKV  = (unsigned short*)p;            p += (size_t)8192 * 1536 * 2;
  unsigned short* VT   = (unsigned short*)p;            p += (size_t)32 * 64 * 2048 * 2;
  unsigned short* CTX  = (unsigned short*)p;            p += (size_t)8192 * 512 * 2;
  unsigned short* Wq   = (unsigned short*)p;            p += (size_t)4 * 1536 * 512 * 2;
  unsigned short* Wo   = (unsigned short*)p;            p += (size_t)4 * 512 * 512 * 2;
  unsigned short* W1   = (unsigned short*)p;            p += (size_t)4 * 512 * 512 * 2;
  unsigned short* W2   = (unsigned short*)p;            p += (size_t)4 * 512 * 512 * 2;
  unsigned short* Wp   = (unsigned short*)p;            p += (size_t)32 * 512 * 2;
  unsigned short* D = QKV;   // aliased: D[8192,512] bf16 in QKV region (disjoint lifetime)

  cvt_all<<<6160, 256, 0, stream>>>(qkv_w, out_w, fc1_w, fc2_w, outp_w, Wq);

  conv_pe_kernel<<<1024, 256, 0, stream>>>(x, conv_w, conv_b, A);

  for (int l = 0; l < 4; l++) {
    gemm_bf<0, 1, 4, 1><<<64 * 12, 256, 0, stream>>>(
        A, Wq + (size_t)l * 1536 * 512, qkv_b + l * 1536, nullptr,
        QKV, nullptr, VT, 1536);
    attn_mfma<<<512, 256, 0, stream>>>(QKV, VT, CTX);
    gemm_bf<1, 0, 2, 0><<<64 * 8, 256, 0, stream>>>(
        CTX, Wo + (size_t)l * 512 * 512, out_b + l * 512, A,
        D, nullptr, nullptr, 512);
    ln_kernel<<<2048, 256, 0, stream>>>(D, ln1_w + l * 512, ln1_b + l * 512, A);
    gemm_bf<2, 0, 2, 0><<<64 * 8, 256, 0, stream>>>(
        A, W1 + (size_t)l * 512 * 512, fc1_b + l * 512, nullptr,
        CTX, nullptr, nullptr, 512);
    gemm_bf<1, 0, 2, 0><<<64 * 8, 256, 0, stream>>>(
        CTX, W2 + (size_t)l * 512 * 512, fc2_b + l * 512, A,
        D, nullptr, nullptr, 512);
    ln_kernel<<<2048, 256, 0, stream>>>(D, ln2_w + l * 512, ln2_b + l * 512, A);
  }
  gemm_bf<3, 0, 1, 0><<<64, 256, 0, stream>>>(
      A, Wp, outp_b, nullptr, nullptr, out, nullptr, 32);
}